// Round 5
// baseline (180.337 us; speedup 1.0000x reference)
//
#include <hip/hip_runtime.h>
#include <math.h>

// Problem constants
#define K_CODES 1024
#define C_DIM   128
#define HW      4096          // 64*64
#define CHW     (C_DIM*HW)    // per-batch stride in x
#define N_POS   65536         // 16*64*64
#define Q_ELEMS 8388608       // 16*128*64*64

// ws layout (byte offsets). Total < 272 KB (proven safe rounds 1-4).
#define WS_S    0             // float: sum of sqrt(d2min)
#define WS_C2   256           // float[1024]: ||c_k||^2
#define WS_IDX  8192          // int[65536]: final argmin index per position

// d_out scratch (overwritten by write_q later; stream-ordered, safe):
//   offset 0: bf16 codebook, row k at k*256B, granule-col j holds channels of
//   granule (j ^ (k&7))  -> linear global_load_lds staging + conflict-free
//   swizzled ds_read_b128 A-frags.

typedef __attribute__((ext_vector_type(8))) short short8;   // 8 bf16 (4 VGPRs)
typedef __attribute__((ext_vector_type(4))) float f32x4;    // MFMA acc

__device__ __forceinline__ unsigned short f2bf(float f) {   // fp32 -> bf16 RNE
    unsigned u = __float_as_uint(f);
    u += 0x7FFFu + ((u >> 16) & 1u);
    return (unsigned short)(u >> 16);
}

// async global->LDS, 16B per lane; LDS dst = wave-uniform base + lane*16
__device__ __forceinline__ void gll16(const void* g, void* l) {
    __builtin_amdgcn_global_load_lds(
        (const __attribute__((address_space(1))) void*)g,
        (__attribute__((address_space(3))) void*)l, 16, 0, 0);
}

// ---------------------------------------------------------------------------
// Kernel 1: prep. Block k (64 lanes): row norm (same math as rounds 1-4),
// bf16 conversion into the COLUMN-SWIZZLED global layout, S zeroing.
// ---------------------------------------------------------------------------
__global__ void prep_kernel(const float* __restrict__ cb, float* __restrict__ ws,
                            unsigned short* __restrict__ cbbf) {
    __shared__ __align__(16) unsigned short srow[128];
    int k = blockIdx.x;
    int l = threadIdx.x;                       // 64 lanes = 1 wave
    if (k == 0 && l == 0) *(float*)((char*)ws + WS_S) = 0.f;
    float v1 = cb[k * C_DIM + l];
    float v2 = cb[k * C_DIM + 64 + l];
    int c1 = l, c2 = 64 + l;
    srow[(((c1 >> 3) ^ (k & 7)) << 3) | (c1 & 7)] = f2bf(v1);
    srow[(((c2 >> 3) ^ (k & 7)) << 3) | (c2 & 7)] = f2bf(v2);
    float ss = v1 * v1 + v2 * v2;
    #pragma unroll
    for (int off = 32; off > 0; off >>= 1) ss += __shfl_down(ss, off);
    if (l == 0) ((float*)((char*)ws + WS_C2))[k] = ss;
    __syncthreads();
    if (l < 16) ((uint4*)cbbf)[k * 16 + l] = ((const uint4*)srow)[l];
}

// ---------------------------------------------------------------------------
// Kernel 2: fused VQ. 1024 blocks x 256 thr. Block = 64 positions x all codes.
// Wave (pg,kh): pg = 32-position group (2 pos-tiles), kh = 512-code half
// -> 4096 waves total = 16 waves/CU (vs 8 in R3/R4).
// Per kh: 8 chunks of 64 codes, single-buffered 16 KB LDS staged via
// global_load_lds (16B), pre-swizzled layout -> conflict-free ds_read_b128.
// Top-3: idx embedded in low 10 mantissa bits, min+2x med3 chain (5 ops).
// kh=1 publishes chains via LDS; kh=0 merges + exact fp32 rescore (x re-read
// from L1/L2, same fmaf order as R4 which passed) + idx + loss.
// ---------------------------------------------------------------------------
__global__ __launch_bounds__(256, 4) void vq_mfma(const float* __restrict__ x,
                                                  const float* __restrict__ cb,
                                                  const unsigned short* __restrict__ cbbf,
                                                  const float* __restrict__ c2w,
                                                  int* __restrict__ idxw,
                                                  float* __restrict__ Sw) {
    __shared__ __align__(16) unsigned short cbuf[2 * 1024 * 8];  // 32 KB
    __shared__ float mbuf[2][2][16][3];                          // 768 B

    const int t  = threadIdx.x;
    const int w  = t >> 6;                      // wave 0..3
    const int kh = w & 1;                       // code half
    const int pg = w >> 1;                      // position group (32 pos)
    const int ln = t & 63;
    const int lp = ln & 15;                     // position lane (n index)
    const int q  = ln >> 4;                     // quad 0..3 (k sub-range)
    const int bid = blockIdx.x;
    const int b   = bid >> 6;                   // batch (64 blocks per image)
    const int s0  = (bid & 63) << 6;            // 64-position tile start

    // ---- x: bf16 B-frags (2 pos-tiles) + per-position norms ----
    short8 xf[2][4];
    float  r2v[2];
    {
        float ss[2] = {0.f, 0.f};
        #pragma unroll
        for (int pt = 0; pt < 2; ++pt) {
            const float* xgp = x + b * CHW + s0 + pg * 32 + pt * 16 + lp;
            #pragma unroll
            for (int cs = 0; cs < 4; ++cs) {
                union { short8 v; unsigned short u[8]; } fu;
                #pragma unroll
                for (int j = 0; j < 8; ++j) {
                    float vv = xgp[(32 * cs + 8 * q + j) * HW];
                    ss[pt] = fmaf(vv, vv, ss[pt]);
                    fu.u[j] = f2bf(vv);
                }
                xf[pt][cs] = fu.v;
            }
        }
        #pragma unroll
        for (int pt = 0; pt < 2; ++pt) {
            float s = ss[pt];
            s += __shfl_xor(s, 16);
            s += __shfl_xor(s, 32);
            r2v[pt] = -2.0f / fmaxf(sqrtf(s), 1e-12f);  // F.normalize eps
        }
    }

    const float FMAX = __uint_as_float(0x7F7FFFFFu);
    float m1[2] = {FMAX, FMAX}, m2[2] = {FMAX, FMAX}, m3[2] = {FMAX, FMAX};

    // staging bases: per-lane global addr, wave-uniform LDS base
    const char* gbase = (const char*)cbbf + (kh * 512) * 256 + (pg * 512 + ln) * 16;
    char* lbase = (char*)cbuf + (kh * 1024 + pg * 512) * 16;

    #pragma unroll
    for (int r = 0; r < 8; ++r)                  // stage chunk 0
        gll16(gbase + r * 1024, lbase + r * 1024);
    __syncthreads();

    for (int i = 0; i < 8; ++i) {
        const int k0 = kh * 512 + i * 64;

        f32x4 acc[4][2];
        #pragma unroll
        for (int ct = 0; ct < 4; ++ct)
            #pragma unroll
            for (int pt = 0; pt < 2; ++pt) acc[ct][pt] = 0;

        const unsigned short* cbp = cbuf + kh * 8192;
        #pragma unroll
        for (int cs = 0; cs < 4; ++cs) {
            short8 ah[4];
            #pragma unroll
            for (int ct = 0; ct < 4; ++ct) {     // A[m=16ct+lp][k=32cs+8q+j]
                int g = (16 * ct + lp) * 16 + ((4 * cs + q) ^ (lp & 7));
                ah[ct] = *(const short8*)(cbp + g * 8);
            }
            #pragma unroll
            for (int ct = 0; ct < 4; ++ct)
                #pragma unroll
                for (int pt = 0; pt < 2; ++pt)
                    acc[ct][pt] = __builtin_amdgcn_mfma_f32_16x16x32_bf16(
                        ah[ct], xf[pt][cs], acc[ct][pt], 0, 0, 0);
        }

        // ---- epilogue: 32 scores, ~5 VALU each ----
        #pragma unroll
        for (int ct = 0; ct < 4; ++ct) {
            float4 c2vv = *(const float4*)(c2w + k0 + 16 * ct + 4 * q);
            float c2a[4] = {c2vv.x, c2vv.y, c2vv.z, c2vv.w};
            const int kb0 = k0 + 16 * ct + 4 * q;
            #pragma unroll
            for (int pt = 0; pt < 2; ++pt) {
                #pragma unroll
                for (int reg = 0; reg < 4; ++reg) {
                    float s = fmaf(r2v[pt], acc[ct][pt][reg], c2a[reg]);
                    unsigned pb = (__float_as_uint(s) & 0xFFFFFC00u) |
                                  (unsigned)(kb0 + reg);
                    float u  = __uint_as_float(pb);
                    float t3 = __builtin_amdgcn_fmed3f(m2[pt], m3[pt], u);
                    float t2 = __builtin_amdgcn_fmed3f(m1[pt], m2[pt], u);
                    m1[pt] = fminf(m1[pt], u); m2[pt] = t2; m3[pt] = t3;
                }
            }
        }

        if (i < 7) {
            __syncthreads();                     // all reads of buffer done
            #pragma unroll
            for (int r = 0; r < 8; ++r)
                gll16(gbase + (i + 1) * 16384 + r * 1024, lbase + r * 1024);
            __syncthreads();                     // loads landed (vmcnt drain)
        }
    }

    // ---- merge chains across the 4 quad-lanes (butterfly: all lanes get it) --
    #pragma unroll
    for (int d = 16; d <= 32; d <<= 1) {
        #pragma unroll
        for (int pt = 0; pt < 2; ++pt) {
            float o1 = __shfl_xor(m1[pt], d), o2 = __shfl_xor(m2[pt], d),
                  o3 = __shfl_xor(m3[pt], d);
            float u, t2, t3;
            u = o1; t3 = __builtin_amdgcn_fmed3f(m2[pt], m3[pt], u);
            t2 = __builtin_amdgcn_fmed3f(m1[pt], m2[pt], u);
            m1[pt] = fminf(m1[pt], u); m2[pt] = t2; m3[pt] = t3;
            u = o2; t3 = __builtin_amdgcn_fmed3f(m2[pt], m3[pt], u);
            t2 = __builtin_amdgcn_fmed3f(m1[pt], m2[pt], u);
            m1[pt] = fminf(m1[pt], u); m2[pt] = t2; m3[pt] = t3;
            u = o3; t3 = __builtin_amdgcn_fmed3f(m2[pt], m3[pt], u);
            t2 = __builtin_amdgcn_fmed3f(m1[pt], m2[pt], u);
            m1[pt] = fminf(m1[pt], u); m2[pt] = t2; m3[pt] = t3;
        }
    }

    if (kh == 1 && ln < 16) {
        #pragma unroll
        for (int pt = 0; pt < 2; ++pt) {
            mbuf[pg][pt][lp][0] = m1[pt];
            mbuf[pg][pt][lp][1] = m2[pt];
            mbuf[pg][pt][lp][2] = m3[pt];
        }
    }
    __syncthreads();

    if (kh == 0) {
        float lsum = 0.f;
        #pragma unroll
        for (int pt = 0; pt < 2; ++pt) {
            // merge the kh=1 half's chain (broadcast LDS reads)
            #pragma unroll
            for (int c = 0; c < 3; ++c) {
                float u  = mbuf[pg][pt][lp][c];
                float t3 = __builtin_amdgcn_fmed3f(m2[pt], m3[pt], u);
                float t2 = __builtin_amdgcn_fmed3f(m1[pt], m2[pt], u);
                m1[pt] = fminf(m1[pt], u); m2[pt] = t2; m3[pt] = t3;
            }
            int ks[3] = {(int)(__float_as_uint(m1[pt]) & 1023u),
                         (int)(__float_as_uint(m2[pt]) & 1023u),
                         (int)(__float_as_uint(m3[pt]) & 1023u)};

            // re-read this position's 32 channels (L1/L2-hot)
            float xr[32];
            const float* xgp = x + b * CHW + s0 + pg * 32 + pt * 16 + lp;
            #pragma unroll
            for (int cs = 0; cs < 4; ++cs)
                #pragma unroll
                for (int j = 0; j < 8; ++j)
                    xr[cs * 8 + j] = xgp[(32 * cs + 8 * q + j) * HW];

            // exact fp32 rescore of the 3 candidates (same order as R4)
            float dots[3];
            #pragma unroll
            for (int jj = 0; jj < 3; ++jj) {
                const float* crow = cb + ks[jj] * C_DIM + 8 * q;
                float p = 0.f;
                #pragma unroll
                for (int cs = 0; cs < 4; ++cs) {
                    float4 a0 = *(const float4*)(crow + 32 * cs);
                    float4 a1 = *(const float4*)(crow + 32 * cs + 4);
                    p = fmaf(xr[cs*8+0], a0.x, p); p = fmaf(xr[cs*8+1], a0.y, p);
                    p = fmaf(xr[cs*8+2], a0.z, p); p = fmaf(xr[cs*8+3], a0.w, p);
                    p = fmaf(xr[cs*8+4], a1.x, p); p = fmaf(xr[cs*8+5], a1.y, p);
                    p = fmaf(xr[cs*8+6], a1.z, p); p = fmaf(xr[cs*8+7], a1.w, p);
                }
                p += __shfl_xor(p, 16);
                p += __shfl_xor(p, 32);
                dots[jj] = p;
            }
            float sb = fmaf(r2v[pt], dots[0], c2w[ks[0]]); int kb = ks[0];
            float s2 = fmaf(r2v[pt], dots[1], c2w[ks[1]]);
            if (s2 < sb || (s2 == sb && ks[1] < kb)) { sb = s2; kb = ks[1]; }
            float s3 = fmaf(r2v[pt], dots[2], c2w[ks[2]]);
            if (s3 < sb || (s3 == sb && ks[2] < kb)) { sb = s3; kb = ks[2]; }

            if (ln < 16) idxw[bid * 64 + pg * 32 + pt * 16 + lp] = kb;
            lsum += sqrtf(fmaxf(1.0f + sb, 0.f));   // z2 == 1 after normalize
        }
        // each position counted by its 4 q-lanes -> scale 0.25
        #pragma unroll
        for (int off = 32; off > 0; off >>= 1) lsum += __shfl_down(lsum, off);
        if (ln == 0) atomicAdd(Sw, 0.25f * lsum);
    }
}

// ---------------------------------------------------------------------------
// Kernel 3: scatter q = codebook[idx] back to [B,C,H,W] (overwrites scratch)
// ---------------------------------------------------------------------------
__global__ void write_q(const float* __restrict__ cb,
                        const float* __restrict__ ws,
                        float* __restrict__ out) {
    const int* idxw = (const int*)((const char*)ws + WS_IDX);
    int e = blockIdx.x * 256 + threadIdx.x;   // float4 id, 2097152 total
    int f = e << 2;
    int s = f & 4095;
    int c = (f >> 12) & 127;
    int b = f >> 19;
    int4 iv = *(const int4*)(idxw + b * HW + s);
    float4 o;
    o.x = cb[iv.x * C_DIM + c];
    o.y = cb[iv.y * C_DIM + c];
    o.z = cb[iv.z * C_DIM + c];
    o.w = cb[iv.w * C_DIM + c];
    ((float4*)out)[e] = o;
}

// ---------------------------------------------------------------------------
// Kernel 4: finalize losses. loss = mean over N of sqrt(d2min); lw=(0.25, 1.0)
// ---------------------------------------------------------------------------
__global__ void fin_kernel(const float* __restrict__ ws, float* __restrict__ out) {
    float S = *(const float*)((const char*)ws + WS_S);
    float m = S / (float)N_POS;
    out[Q_ELEMS]     = 0.25f * m;
    out[Q_ELEMS + 1] = m;
}

extern "C" void kernel_launch(void* const* d_in, const int* in_sizes, int n_in,
                              void* d_out, int out_size, void* d_ws, size_t ws_size,
                              hipStream_t stream) {
    const float* x  = (const float*)d_in[0];   // [16,128,64,64]
    const float* cb = (const float*)d_in[1];   // [1024,128]
    float* out = (float*)d_out;
    float* ws  = (float*)d_ws;

    const float* c2w = (const float*)((const char*)d_ws + WS_C2);
    int*  idxw = (int*)((char*)d_ws + WS_IDX);
    float* Sw  = (float*)((char*)d_ws + WS_S);
    unsigned short* cbbf = (unsigned short*)d_out;   // scratch in d_out

    prep_kernel<<<K_CODES, 64, 0, stream>>>(cb, ws, cbbf);
    vq_mfma    <<<N_POS / 64, 256, 0, stream>>>(x, cb, cbbf, c2w, idxw, Sw);
    write_q    <<<Q_ELEMS / 1024, 256, 0, stream>>>(cb, ws, out);
    fin_kernel <<<1, 1, 0, stream>>>(ws, out);
}

// Round 6
// 144.060 us; speedup vs baseline: 1.2518x; 1.2518x over previous
//
#include <hip/hip_runtime.h>
#include <math.h>

// Problem constants
#define K_CODES 1024
#define C_DIM   128
#define HW      4096          // 64*64
#define CHW     (C_DIM*HW)    // per-batch stride in x
#define N_POS   65536         // 16*64*64
#define Q_ELEMS 8388608       // 16*128*64*64

// ws layout (byte offsets). Total < 272 KB (proven safe rounds 1-5).
#define WS_S    0             // float: sum of sqrt(d2min)
#define WS_C2   256           // float[1024]: ||c_k||^2
#define WS_IDX  8192          // int[65536]: final argmin index per position

// d_out scratch (overwritten by write_q later; stream-ordered, safe):
//   offset 0: bf16 codebook, row k at k*256B, granule-col j holds channels of
//   granule (j ^ (k&7))  -> linear global_load_lds staging + conflict-free
//   swizzled ds_read_b128 A-frags.

typedef __attribute__((ext_vector_type(8))) short short8;   // 8 bf16 (4 VGPRs)
typedef __attribute__((ext_vector_type(4))) float f32x4;    // MFMA acc

__device__ __forceinline__ unsigned short f2bf(float f) {   // fp32 -> bf16 RNE
    unsigned u = __float_as_uint(f);
    u += 0x7FFFu + ((u >> 16) & 1u);
    return (unsigned short)(u >> 16);
}

// async global->LDS, 16B per lane; LDS dst = wave-uniform base + lane*16
__device__ __forceinline__ void gll16(const void* g, void* l) {
    __builtin_amdgcn_global_load_lds(
        (const __attribute__((address_space(1))) void*)g,
        (__attribute__((address_space(3))) void*)l, 16, 0, 0);
}

// ---------------------------------------------------------------------------
// Kernel 1: prep. Block k (64 lanes): row norm (same math as rounds 1-5),
// bf16 conversion into the COLUMN-SWIZZLED global layout, S zeroing.
// ---------------------------------------------------------------------------
__global__ void prep_kernel(const float* __restrict__ cb, float* __restrict__ ws,
                            unsigned short* __restrict__ cbbf) {
    __shared__ __align__(16) unsigned short srow[128];
    int k = blockIdx.x;
    int l = threadIdx.x;                       // 64 lanes = 1 wave
    if (k == 0 && l == 0) *(float*)((char*)ws + WS_S) = 0.f;
    float v1 = cb[k * C_DIM + l];
    float v2 = cb[k * C_DIM + 64 + l];
    int c1 = l, c2 = 64 + l;
    srow[(((c1 >> 3) ^ (k & 7)) << 3) | (c1 & 7)] = f2bf(v1);
    srow[(((c2 >> 3) ^ (k & 7)) << 3) | (c2 & 7)] = f2bf(v2);
    float ss = v1 * v1 + v2 * v2;
    #pragma unroll
    for (int off = 32; off > 0; off >>= 1) ss += __shfl_down(ss, off);
    if (l == 0) ((float*)((char*)ws + WS_C2))[k] = ss;
    __syncthreads();
    if (l < 16) ((uint4*)cbbf)[k * 16 + l] = ((const uint4*)srow)[l];
}

// ---------------------------------------------------------------------------
// Kernel 2: fused VQ. 1024 blocks x 256 thr. Block = 64 positions x all codes.
// Wave (pg,kh): pg = 32-position group (2 pos-tiles), kh = 512-code half
// -> 4096 waves total; LDS 33.8 KB -> 4 blocks/CU if VGPR<=128.
// __launch_bounds__(256,2): VGPR ceiling 256 -- R5's (256,4) squeezed the
// allocator to 64 regs and spilled ~180 MB of scratch to HBM (WRITE_SIZE
// 123 MB); the min-waves arg is a pressure bound, not a target.
// Per kh: 8 chunks of 64 codes, single-buffered 16 KB LDS staged via
// global_load_lds (16B), pre-swizzled layout -> conflict-free ds_read_b128.
// Top-3: idx embedded in low 10 mantissa bits, min+2x med3 chain (5 ops).
// kh=1 publishes chains via LDS; kh=0 merges + exact fp32 rescore (x re-read
// from L1/L2, same fmaf order as R4/R5 which passed) + idx + loss.
// ---------------------------------------------------------------------------
__global__ __launch_bounds__(256, 2) void vq_mfma(const float* __restrict__ x,
                                                  const float* __restrict__ cb,
                                                  const unsigned short* __restrict__ cbbf,
                                                  const float* __restrict__ c2w,
                                                  int* __restrict__ idxw,
                                                  float* __restrict__ Sw) {
    __shared__ __align__(16) unsigned short cbuf[2 * 1024 * 8];  // 32 KB
    __shared__ float mbuf[2][2][16][3];                          // 768 B

    const int t  = threadIdx.x;
    const int w  = t >> 6;                      // wave 0..3
    const int kh = w & 1;                       // code half
    const int pg = w >> 1;                      // position group (32 pos)
    const int ln = t & 63;
    const int lp = ln & 15;                     // position lane (n index)
    const int q  = ln >> 4;                     // quad 0..3 (k sub-range)
    const int bid = blockIdx.x;
    const int b   = bid >> 6;                   // batch (64 blocks per image)
    const int s0  = (bid & 63) << 6;            // 64-position tile start

    // ---- x: bf16 B-frags (2 pos-tiles) + per-position norms ----
    short8 xf[2][4];
    float  r2v[2];
    {
        float ss[2] = {0.f, 0.f};
        #pragma unroll
        for (int pt = 0; pt < 2; ++pt) {
            const float* xgp = x + b * CHW + s0 + pg * 32 + pt * 16 + lp;
            #pragma unroll
            for (int cs = 0; cs < 4; ++cs) {
                union { short8 v; unsigned short u[8]; } fu;
                #pragma unroll
                for (int j = 0; j < 8; ++j) {
                    float vv = xgp[(32 * cs + 8 * q + j) * HW];
                    ss[pt] = fmaf(vv, vv, ss[pt]);
                    fu.u[j] = f2bf(vv);
                }
                xf[pt][cs] = fu.v;
            }
        }
        #pragma unroll
        for (int pt = 0; pt < 2; ++pt) {
            float s = ss[pt];
            s += __shfl_xor(s, 16);
            s += __shfl_xor(s, 32);
            r2v[pt] = -2.0f / fmaxf(sqrtf(s), 1e-12f);  // F.normalize eps
        }
    }

    const float FMAX = __uint_as_float(0x7F7FFFFFu);
    float m1[2] = {FMAX, FMAX}, m2[2] = {FMAX, FMAX}, m3[2] = {FMAX, FMAX};

    // staging bases: per-lane global addr, wave-uniform LDS base
    const char* gbase = (const char*)cbbf + (kh * 512) * 256 + (pg * 512 + ln) * 16;
    char* lbase = (char*)cbuf + (kh * 1024 + pg * 512) * 16;

    #pragma unroll
    for (int r = 0; r < 8; ++r)                  // stage chunk 0
        gll16(gbase + r * 1024, lbase + r * 1024);
    __syncthreads();

    for (int i = 0; i < 8; ++i) {
        const int k0 = kh * 512 + i * 64;

        f32x4 acc[4][2];
        #pragma unroll
        for (int ct = 0; ct < 4; ++ct)
            #pragma unroll
            for (int pt = 0; pt < 2; ++pt) acc[ct][pt] = 0;

        const unsigned short* cbp = cbuf + kh * 8192;
        #pragma unroll
        for (int cs = 0; cs < 4; ++cs) {
            short8 ah[4];
            #pragma unroll
            for (int ct = 0; ct < 4; ++ct) {     // A[m=16ct+lp][k=32cs+8q+j]
                int g = (16 * ct + lp) * 16 + ((4 * cs + q) ^ (lp & 7));
                ah[ct] = *(const short8*)(cbp + g * 8);
            }
            #pragma unroll
            for (int ct = 0; ct < 4; ++ct)
                #pragma unroll
                for (int pt = 0; pt < 2; ++pt)
                    acc[ct][pt] = __builtin_amdgcn_mfma_f32_16x16x32_bf16(
                        ah[ct], xf[pt][cs], acc[ct][pt], 0, 0, 0);
        }

        // ---- epilogue: 32 scores, ~5 VALU each (fmaf, and_or, 2 med3, min) --
        #pragma unroll
        for (int ct = 0; ct < 4; ++ct) {
            float4 c2vv = *(const float4*)(c2w + k0 + 16 * ct + 4 * q);
            float c2a[4] = {c2vv.x, c2vv.y, c2vv.z, c2vv.w};
            const int kb0 = k0 + 16 * ct + 4 * q;
            #pragma unroll
            for (int pt = 0; pt < 2; ++pt) {
                #pragma unroll
                for (int reg = 0; reg < 4; ++reg) {
                    float s = fmaf(r2v[pt], acc[ct][pt][reg], c2a[reg]);
                    unsigned pb = (__float_as_uint(s) & 0xFFFFFC00u) |
                                  (unsigned)(kb0 + reg);
                    float u  = __uint_as_float(pb);
                    float t3 = __builtin_amdgcn_fmed3f(m2[pt], m3[pt], u);
                    float t2 = __builtin_amdgcn_fmed3f(m1[pt], m2[pt], u);
                    m1[pt] = fminf(m1[pt], u); m2[pt] = t2; m3[pt] = t3;
                }
            }
        }

        if (i < 7) {
            __syncthreads();                     // all reads of buffer done
            #pragma unroll
            for (int r = 0; r < 8; ++r)
                gll16(gbase + (i + 1) * 16384 + r * 1024, lbase + r * 1024);
            __syncthreads();                     // loads landed (vmcnt drain)
        }
    }

    // ---- merge chains across the 4 quad-lanes (butterfly: all lanes get it) --
    #pragma unroll
    for (int d = 16; d <= 32; d <<= 1) {
        #pragma unroll
        for (int pt = 0; pt < 2; ++pt) {
            float o1 = __shfl_xor(m1[pt], d), o2 = __shfl_xor(m2[pt], d),
                  o3 = __shfl_xor(m3[pt], d);
            float u, t2, t3;
            u = o1; t3 = __builtin_amdgcn_fmed3f(m2[pt], m3[pt], u);
            t2 = __builtin_amdgcn_fmed3f(m1[pt], m2[pt], u);
            m1[pt] = fminf(m1[pt], u); m2[pt] = t2; m3[pt] = t3;
            u = o2; t3 = __builtin_amdgcn_fmed3f(m2[pt], m3[pt], u);
            t2 = __builtin_amdgcn_fmed3f(m1[pt], m2[pt], u);
            m1[pt] = fminf(m1[pt], u); m2[pt] = t2; m3[pt] = t3;
            u = o3; t3 = __builtin_amdgcn_fmed3f(m2[pt], m3[pt], u);
            t2 = __builtin_amdgcn_fmed3f(m1[pt], m2[pt], u);
            m1[pt] = fminf(m1[pt], u); m2[pt] = t2; m3[pt] = t3;
        }
    }

    if (kh == 1 && ln < 16) {
        #pragma unroll
        for (int pt = 0; pt < 2; ++pt) {
            mbuf[pg][pt][lp][0] = m1[pt];
            mbuf[pg][pt][lp][1] = m2[pt];
            mbuf[pg][pt][lp][2] = m3[pt];
        }
    }
    __syncthreads();

    if (kh == 0) {
        float lsum = 0.f;
        #pragma unroll
        for (int pt = 0; pt < 2; ++pt) {
            // merge the kh=1 half's chain (broadcast LDS reads)
            #pragma unroll
            for (int c = 0; c < 3; ++c) {
                float u  = mbuf[pg][pt][lp][c];
                float t3 = __builtin_amdgcn_fmed3f(m2[pt], m3[pt], u);
                float t2 = __builtin_amdgcn_fmed3f(m1[pt], m2[pt], u);
                m1[pt] = fminf(m1[pt], u); m2[pt] = t2; m3[pt] = t3;
            }
            int ks[3] = {(int)(__float_as_uint(m1[pt]) & 1023u),
                         (int)(__float_as_uint(m2[pt]) & 1023u),
                         (int)(__float_as_uint(m3[pt]) & 1023u)};

            // re-read this position's 32 channels (L1/L2-hot)
            float xr[32];
            const float* xgp = x + b * CHW + s0 + pg * 32 + pt * 16 + lp;
            #pragma unroll
            for (int cs = 0; cs < 4; ++cs)
                #pragma unroll
                for (int j = 0; j < 8; ++j)
                    xr[cs * 8 + j] = xgp[(32 * cs + 8 * q + j) * HW];

            // exact fp32 rescore of the 3 candidates (same order as R4/R5)
            float dots[3];
            #pragma unroll
            for (int jj = 0; jj < 3; ++jj) {
                const float* crow = cb + ks[jj] * C_DIM + 8 * q;
                float p = 0.f;
                #pragma unroll
                for (int cs = 0; cs < 4; ++cs) {
                    float4 a0 = *(const float4*)(crow + 32 * cs);
                    float4 a1 = *(const float4*)(crow + 32 * cs + 4);
                    p = fmaf(xr[cs*8+0], a0.x, p); p = fmaf(xr[cs*8+1], a0.y, p);
                    p = fmaf(xr[cs*8+2], a0.z, p); p = fmaf(xr[cs*8+3], a0.w, p);
                    p = fmaf(xr[cs*8+4], a1.x, p); p = fmaf(xr[cs*8+5], a1.y, p);
                    p = fmaf(xr[cs*8+6], a1.z, p); p = fmaf(xr[cs*8+7], a1.w, p);
                }
                p += __shfl_xor(p, 16);
                p += __shfl_xor(p, 32);
                dots[jj] = p;
            }
            float sb = fmaf(r2v[pt], dots[0], c2w[ks[0]]); int kb = ks[0];
            float s2 = fmaf(r2v[pt], dots[1], c2w[ks[1]]);
            if (s2 < sb || (s2 == sb && ks[1] < kb)) { sb = s2; kb = ks[1]; }
            float s3 = fmaf(r2v[pt], dots[2], c2w[ks[2]]);
            if (s3 < sb || (s3 == sb && ks[2] < kb)) { sb = s3; kb = ks[2]; }

            if (ln < 16) idxw[bid * 64 + pg * 32 + pt * 16 + lp] = kb;
            lsum += sqrtf(fmaxf(1.0f + sb, 0.f));   // z2 == 1 after normalize
        }
        // each position counted by its 4 q-lanes -> scale 0.25
        #pragma unroll
        for (int off = 32; off > 0; off >>= 1) lsum += __shfl_down(lsum, off);
        if (ln == 0) atomicAdd(Sw, 0.25f * lsum);
    }
}

// ---------------------------------------------------------------------------
// Kernel 3: scatter q = codebook[idx] back to [B,C,H,W] (overwrites scratch)
// ---------------------------------------------------------------------------
__global__ void write_q(const float* __restrict__ cb,
                        const float* __restrict__ ws,
                        float* __restrict__ out) {
    const int* idxw = (const int*)((const char*)ws + WS_IDX);
    int e = blockIdx.x * 256 + threadIdx.x;   // float4 id, 2097152 total
    int f = e << 2;
    int s = f & 4095;
    int c = (f >> 12) & 127;
    int b = f >> 19;
    int4 iv = *(const int4*)(idxw + b * HW + s);
    float4 o;
    o.x = cb[iv.x * C_DIM + c];
    o.y = cb[iv.y * C_DIM + c];
    o.z = cb[iv.z * C_DIM + c];
    o.w = cb[iv.w * C_DIM + c];
    ((float4*)out)[e] = o;
}

// ---------------------------------------------------------------------------
// Kernel 4: finalize losses. loss = mean over N of sqrt(d2min); lw=(0.25, 1.0)
// ---------------------------------------------------------------------------
__global__ void fin_kernel(const float* __restrict__ ws, float* __restrict__ out) {
    float S = *(const float*)((const char*)ws + WS_S);
    float m = S / (float)N_POS;
    out[Q_ELEMS]     = 0.25f * m;
    out[Q_ELEMS + 1] = m;
}

extern "C" void kernel_launch(void* const* d_in, const int* in_sizes, int n_in,
                              void* d_out, int out_size, void* d_ws, size_t ws_size,
                              hipStream_t stream) {
    const float* x  = (const float*)d_in[0];   // [16,128,64,64]
    const float* cb = (const float*)d_in[1];   // [1024,128]
    float* out = (float*)d_out;
    float* ws  = (float*)d_ws;

    const float* c2w = (const float*)((const char*)d_ws + WS_C2);
    int*  idxw = (int*)((char*)d_ws + WS_IDX);
    float* Sw  = (float*)((char*)d_ws + WS_S);
    unsigned short* cbbf = (unsigned short*)d_out;   // scratch in d_out

    prep_kernel<<<K_CODES, 64, 0, stream>>>(cb, ws, cbbf);
    vq_mfma    <<<N_POS / 64, 256, 0, stream>>>(x, cb, cbbf, c2w, idxw, Sw);
    write_q    <<<Q_ELEMS / 1024, 256, 0, stream>>>(cb, ws, out);
    fin_kernel <<<1, 1, 0, stream>>>(ws, out);
}

// Round 7
// 139.886 us; speedup vs baseline: 1.2892x; 1.0298x over previous
//
#include <hip/hip_runtime.h>
#include <math.h>

// Problem constants
#define K_CODES 1024
#define C_DIM   128
#define HW      4096          // 64*64
#define CHW     (C_DIM*HW)    // per-batch stride in x
#define N_POS   65536         // 16*64*64
#define Q_ELEMS 8388608       // 16*128*64*64

// ws layout (byte offsets). Total < 272 KB (proven safe rounds 1-6).
#define WS_S    0             // float: sum of sqrt(d2min)
#define WS_C2   256           // float[1024]: ||c_k||^2
#define WS_IDX  8192          // int[65536]: final argmin index per position
                              // idxw[p] == argmin for (batch p>>12, spatial p&4095)

// d_out scratch (overwritten by write_q later; stream-ordered, safe):
//   offset 0: bf16 codebook, row k at k*256B, granule-col j holds channels of
//   granule (j ^ (k&7))  -> linear global_load_lds staging + conflict-free
//   swizzled ds_read_b128 A-frags.

typedef __attribute__((ext_vector_type(8))) short short8;   // 8 bf16 (4 VGPRs)
typedef __attribute__((ext_vector_type(4))) float f32x4;    // MFMA acc

__device__ __forceinline__ unsigned short f2bf(float f) {   // fp32 -> bf16 RNE
    unsigned u = __float_as_uint(f);
    u += 0x7FFFu + ((u >> 16) & 1u);
    return (unsigned short)(u >> 16);
}

// async global->LDS, 16B per lane; LDS dst = wave-uniform base + lane*16
__device__ __forceinline__ void gll16(const void* g, void* l) {
    __builtin_amdgcn_global_load_lds(
        (const __attribute__((address_space(1))) void*)g,
        (__attribute__((address_space(3))) void*)l, 16, 0, 0);
}

// ---------------------------------------------------------------------------
// Kernel 1: prep. Block k (64 lanes): row norm (same math as rounds 1-6),
// bf16 conversion into the COLUMN-SWIZZLED global layout, S zeroing.
// ---------------------------------------------------------------------------
__global__ void prep_kernel(const float* __restrict__ cb, float* __restrict__ ws,
                            unsigned short* __restrict__ cbbf) {
    __shared__ __align__(16) unsigned short srow[128];
    int k = blockIdx.x;
    int l = threadIdx.x;                       // 64 lanes = 1 wave
    if (k == 0 && l == 0) *(float*)((char*)ws + WS_S) = 0.f;
    float v1 = cb[k * C_DIM + l];
    float v2 = cb[k * C_DIM + 64 + l];
    int c1 = l, c2 = 64 + l;
    srow[(((c1 >> 3) ^ (k & 7)) << 3) | (c1 & 7)] = f2bf(v1);
    srow[(((c2 >> 3) ^ (k & 7)) << 3) | (c2 & 7)] = f2bf(v2);
    float ss = v1 * v1 + v2 * v2;
    #pragma unroll
    for (int off = 32; off > 0; off >>= 1) ss += __shfl_down(ss, off);
    if (l == 0) ((float*)((char*)ws + WS_C2))[k] = ss;
    __syncthreads();
    if (l < 16) ((uint4*)cbbf)[k * 16 + l] = ((const uint4*)srow)[l];
}

// ---------------------------------------------------------------------------
// Kernel 2: fused VQ (byte-identical to R6, which passed absmax 0.0 @63 us).
// 1024 blocks x 256 thr. Block = 64 positions x all codes. Wave (pg,kh):
// pg = 32-position group, kh = 512-code half. __launch_bounds__(256,2):
// VGPR ceiling 256 -- (256,4) squeezed to 64 regs and spilled ~180 MB (R5).
// Per kh: 8 chunks of 64 codes, single-buffered 16 KB LDS via global_load_lds,
// pre-swizzled layout -> conflict-free ds_read_b128. Top-3 via min+2x med3
// with idx in low 10 mantissa bits; kh=1 publishes chains via LDS; kh=0
// merges + exact fp32 rescore + idx + loss.
// ---------------------------------------------------------------------------
__global__ __launch_bounds__(256, 2) void vq_mfma(const float* __restrict__ x,
                                                  const float* __restrict__ cb,
                                                  const unsigned short* __restrict__ cbbf,
                                                  const float* __restrict__ c2w,
                                                  int* __restrict__ idxw,
                                                  float* __restrict__ Sw) {
    __shared__ __align__(16) unsigned short cbuf[2 * 1024 * 8];  // 32 KB
    __shared__ float mbuf[2][2][16][3];                          // 768 B

    const int t  = threadIdx.x;
    const int w  = t >> 6;                      // wave 0..3
    const int kh = w & 1;                       // code half
    const int pg = w >> 1;                      // position group (32 pos)
    const int ln = t & 63;
    const int lp = ln & 15;                     // position lane (n index)
    const int q  = ln >> 4;                     // quad 0..3 (k sub-range)
    const int bid = blockIdx.x;
    const int b   = bid >> 6;                   // batch (64 blocks per image)
    const int s0  = (bid & 63) << 6;            // 64-position tile start

    // ---- x: bf16 B-frags (2 pos-tiles) + per-position norms ----
    short8 xf[2][4];
    float  r2v[2];
    {
        float ss[2] = {0.f, 0.f};
        #pragma unroll
        for (int pt = 0; pt < 2; ++pt) {
            const float* xgp = x + b * CHW + s0 + pg * 32 + pt * 16 + lp;
            #pragma unroll
            for (int cs = 0; cs < 4; ++cs) {
                union { short8 v; unsigned short u[8]; } fu;
                #pragma unroll
                for (int j = 0; j < 8; ++j) {
                    float vv = xgp[(32 * cs + 8 * q + j) * HW];
                    ss[pt] = fmaf(vv, vv, ss[pt]);
                    fu.u[j] = f2bf(vv);
                }
                xf[pt][cs] = fu.v;
            }
        }
        #pragma unroll
        for (int pt = 0; pt < 2; ++pt) {
            float s = ss[pt];
            s += __shfl_xor(s, 16);
            s += __shfl_xor(s, 32);
            r2v[pt] = -2.0f / fmaxf(sqrtf(s), 1e-12f);  // F.normalize eps
        }
    }

    const float FMAX = __uint_as_float(0x7F7FFFFFu);
    float m1[2] = {FMAX, FMAX}, m2[2] = {FMAX, FMAX}, m3[2] = {FMAX, FMAX};

    // staging bases: per-lane global addr, wave-uniform LDS base
    const char* gbase = (const char*)cbbf + (kh * 512) * 256 + (pg * 512 + ln) * 16;
    char* lbase = (char*)cbuf + (kh * 1024 + pg * 512) * 16;

    #pragma unroll
    for (int r = 0; r < 8; ++r)                  // stage chunk 0
        gll16(gbase + r * 1024, lbase + r * 1024);
    __syncthreads();

    for (int i = 0; i < 8; ++i) {
        const int k0 = kh * 512 + i * 64;

        f32x4 acc[4][2];
        #pragma unroll
        for (int ct = 0; ct < 4; ++ct)
            #pragma unroll
            for (int pt = 0; pt < 2; ++pt) acc[ct][pt] = 0;

        const unsigned short* cbp = cbuf + kh * 8192;
        #pragma unroll
        for (int cs = 0; cs < 4; ++cs) {
            short8 ah[4];
            #pragma unroll
            for (int ct = 0; ct < 4; ++ct) {     // A[m=16ct+lp][k=32cs+8q+j]
                int g = (16 * ct + lp) * 16 + ((4 * cs + q) ^ (lp & 7));
                ah[ct] = *(const short8*)(cbp + g * 8);
            }
            #pragma unroll
            for (int ct = 0; ct < 4; ++ct)
                #pragma unroll
                for (int pt = 0; pt < 2; ++pt)
                    acc[ct][pt] = __builtin_amdgcn_mfma_f32_16x16x32_bf16(
                        ah[ct], xf[pt][cs], acc[ct][pt], 0, 0, 0);
        }

        // ---- epilogue: 32 scores, ~5 VALU each (fmaf, and_or, 2 med3, min) --
        #pragma unroll
        for (int ct = 0; ct < 4; ++ct) {
            float4 c2vv = *(const float4*)(c2w + k0 + 16 * ct + 4 * q);
            float c2a[4] = {c2vv.x, c2vv.y, c2vv.z, c2vv.w};
            const int kb0 = k0 + 16 * ct + 4 * q;
            #pragma unroll
            for (int pt = 0; pt < 2; ++pt) {
                #pragma unroll
                for (int reg = 0; reg < 4; ++reg) {
                    float s = fmaf(r2v[pt], acc[ct][pt][reg], c2a[reg]);
                    unsigned pb = (__float_as_uint(s) & 0xFFFFFC00u) |
                                  (unsigned)(kb0 + reg);
                    float u  = __uint_as_float(pb);
                    float t3 = __builtin_amdgcn_fmed3f(m2[pt], m3[pt], u);
                    float t2 = __builtin_amdgcn_fmed3f(m1[pt], m2[pt], u);
                    m1[pt] = fminf(m1[pt], u); m2[pt] = t2; m3[pt] = t3;
                }
            }
        }

        if (i < 7) {
            __syncthreads();                     // all reads of buffer done
            #pragma unroll
            for (int r = 0; r < 8; ++r)
                gll16(gbase + (i + 1) * 16384 + r * 1024, lbase + r * 1024);
            __syncthreads();                     // loads landed (vmcnt drain)
        }
    }

    // ---- merge chains across the 4 quad-lanes (butterfly: all lanes get it) --
    #pragma unroll
    for (int d = 16; d <= 32; d <<= 1) {
        #pragma unroll
        for (int pt = 0; pt < 2; ++pt) {
            float o1 = __shfl_xor(m1[pt], d), o2 = __shfl_xor(m2[pt], d),
                  o3 = __shfl_xor(m3[pt], d);
            float u, t2, t3;
            u = o1; t3 = __builtin_amdgcn_fmed3f(m2[pt], m3[pt], u);
            t2 = __builtin_amdgcn_fmed3f(m1[pt], m2[pt], u);
            m1[pt] = fminf(m1[pt], u); m2[pt] = t2; m3[pt] = t3;
            u = o2; t3 = __builtin_amdgcn_fmed3f(m2[pt], m3[pt], u);
            t2 = __builtin_amdgcn_fmed3f(m1[pt], m2[pt], u);
            m1[pt] = fminf(m1[pt], u); m2[pt] = t2; m3[pt] = t3;
            u = o3; t3 = __builtin_amdgcn_fmed3f(m2[pt], m3[pt], u);
            t2 = __builtin_amdgcn_fmed3f(m1[pt], m2[pt], u);
            m1[pt] = fminf(m1[pt], u); m2[pt] = t2; m3[pt] = t3;
        }
    }

    if (kh == 1 && ln < 16) {
        #pragma unroll
        for (int pt = 0; pt < 2; ++pt) {
            mbuf[pg][pt][lp][0] = m1[pt];
            mbuf[pg][pt][lp][1] = m2[pt];
            mbuf[pg][pt][lp][2] = m3[pt];
        }
    }
    __syncthreads();

    if (kh == 0) {
        float lsum = 0.f;
        #pragma unroll
        for (int pt = 0; pt < 2; ++pt) {
            // merge the kh=1 half's chain (broadcast LDS reads)
            #pragma unroll
            for (int c = 0; c < 3; ++c) {
                float u  = mbuf[pg][pt][lp][c];
                float t3 = __builtin_amdgcn_fmed3f(m2[pt], m3[pt], u);
                float t2 = __builtin_amdgcn_fmed3f(m1[pt], m2[pt], u);
                m1[pt] = fminf(m1[pt], u); m2[pt] = t2; m3[pt] = t3;
            }
            int ks[3] = {(int)(__float_as_uint(m1[pt]) & 1023u),
                         (int)(__float_as_uint(m2[pt]) & 1023u),
                         (int)(__float_as_uint(m3[pt]) & 1023u)};

            // re-read this position's 32 channels (L1/L2-hot)
            float xr[32];
            const float* xgp = x + b * CHW + s0 + pg * 32 + pt * 16 + lp;
            #pragma unroll
            for (int cs = 0; cs < 4; ++cs)
                #pragma unroll
                for (int j = 0; j < 8; ++j)
                    xr[cs * 8 + j] = xgp[(32 * cs + 8 * q + j) * HW];

            // exact fp32 rescore of the 3 candidates (same order as R4-R6)
            float dots[3];
            #pragma unroll
            for (int jj = 0; jj < 3; ++jj) {
                const float* crow = cb + ks[jj] * C_DIM + 8 * q;
                float p = 0.f;
                #pragma unroll
                for (int cs = 0; cs < 4; ++cs) {
                    float4 a0 = *(const float4*)(crow + 32 * cs);
                    float4 a1 = *(const float4*)(crow + 32 * cs + 4);
                    p = fmaf(xr[cs*8+0], a0.x, p); p = fmaf(xr[cs*8+1], a0.y, p);
                    p = fmaf(xr[cs*8+2], a0.z, p); p = fmaf(xr[cs*8+3], a0.w, p);
                    p = fmaf(xr[cs*8+4], a1.x, p); p = fmaf(xr[cs*8+5], a1.y, p);
                    p = fmaf(xr[cs*8+6], a1.z, p); p = fmaf(xr[cs*8+7], a1.w, p);
                }
                p += __shfl_xor(p, 16);
                p += __shfl_xor(p, 32);
                dots[jj] = p;
            }
            float sb = fmaf(r2v[pt], dots[0], c2w[ks[0]]); int kb = ks[0];
            float s2 = fmaf(r2v[pt], dots[1], c2w[ks[1]]);
            if (s2 < sb || (s2 == sb && ks[1] < kb)) { sb = s2; kb = ks[1]; }
            float s3 = fmaf(r2v[pt], dots[2], c2w[ks[2]]);
            if (s3 < sb || (s3 == sb && ks[2] < kb)) { sb = s3; kb = ks[2]; }

            if (ln < 16) idxw[bid * 64 + pg * 32 + pt * 16 + lp] = kb;
            lsum += sqrtf(fmaxf(1.0f + sb, 0.f));   // z2 == 1 after normalize
        }
        // each position counted by its 4 q-lanes -> scale 0.25
        #pragma unroll
        for (int off = 32; off > 0; off >>= 1) lsum += __shfl_down(lsum, off);
        if (ln == 0) atomicAdd(Sw, 0.25f * lsum);
    }
}

// ---------------------------------------------------------------------------
// Kernel 3: scatter q = codebook[idx] + finalize losses.
// R6's write_q gathered 4B scalars from random rows (33.5M scattered L1
// transactions, ~50 us). v2: thread = (position, channel-quad): ONE float4
// gather from the code row (16B transaction) + 4 wave-coalesced scalar
// stores (fixed c, consecutive s -> 256B segments). 8192 blocks x 256.
// ---------------------------------------------------------------------------
__global__ void write_q(const float* __restrict__ cb,
                        const int* __restrict__ idxw,
                        const float* __restrict__ ws,
                        float* __restrict__ out) {
    int id = blockIdx.x * 256 + threadIdx.x;   // 2,097,152 = N_POS * 32
    int p  = id & (N_POS - 1);                 // position (lanes consecutive)
    int c4 = id >> 16;                         // channel quad 0..31
    int b  = p >> 12, s = p & 4095;
    int row = idxw[p];                         // coalesced 4B reads
    float4 v = ((const float4*)cb)[row * 32 + c4];   // 16B gather, L2-hot
    float* o = out + b * CHW + (c4 * 4) * HW + s;
    o[0]      = v.x;                           // each store: 64 lanes x 4B
    o[HW]     = v.y;                           //  = coalesced 256B segment
    o[2 * HW] = v.z;
    o[3 * HW] = v.w;
    if (id == 0) {                             // fold in loss finalize
        float S = *(const float*)((const char*)ws + WS_S);
        float m = S / (float)N_POS;
        out[Q_ELEMS]     = 0.25f * m;
        out[Q_ELEMS + 1] = m;
    }
}

extern "C" void kernel_launch(void* const* d_in, const int* in_sizes, int n_in,
                              void* d_out, int out_size, void* d_ws, size_t ws_size,
                              hipStream_t stream) {
    const float* x  = (const float*)d_in[0];   // [16,128,64,64]
    const float* cb = (const float*)d_in[1];   // [1024,128]
    float* out = (float*)d_out;
    float* ws  = (float*)d_ws;

    const float* c2w = (const float*)((const char*)d_ws + WS_C2);
    int*  idxw = (int*)((char*)d_ws + WS_IDX);
    float* Sw  = (float*)((char*)d_ws + WS_S);
    unsigned short* cbbf = (unsigned short*)d_out;   // scratch in d_out

    prep_kernel<<<K_CODES, 64, 0, stream>>>(cb, ws, cbbf);
    vq_mfma    <<<N_POS / 64, 256, 0, stream>>>(x, cb, cbbf, c2w, idxw, Sw);
    write_q    <<<Q_ELEMS / 1024, 256, 0, stream>>>(cb, idxw, ws, out);
}